// Round 15
// baseline (450.586 us; speedup 1.0000x reference)
//
#include <hip/hip_runtime.h>
#include <hip/hip_bf16.h>

typedef __attribute__((ext_vector_type(8))) short short8;
typedef __attribute__((ext_vector_type(4))) float f32x4;

static __device__ __forceinline__ f32x4 MFMA16(short8 a, short8 b, f32x4 c) {
    return __builtin_amdgcn_mfma_f32_16x16x32_bf16(a, b, c, 0, 0, 0);
}
static __device__ __forceinline__ unsigned short f2bf(float f) {
    union { __hip_bfloat16 h; unsigned short u; } c;
    c.h = __float2bfloat16(f);
    return c.u;
}
static __device__ __forceinline__ void gload16(const void* g, void* l) {
    __builtin_amdgcn_global_load_lds(
        (const __attribute__((address_space(1))) unsigned int*)g,
        (__attribute__((address_space(3))) unsigned int*)l, 16, 0, 0);
}

// ---------------- ws layout ----------------
// wbf  : bf16, FRAGMENT-ordered w_in [6 hp][6 s][12 f][2 c][64 lanes x16B] @ 0 (884736)
//        lane(g,r16) of frag (f,c): row = f*16+r16 (of 192), k = s*64+c*32+g*8
// wos  : bf16, LDS-order pre-swizzled w_out [3 nb][6 s][1024 gran x16B] @ 884736 (294912)
// brr  : f32  [12][96] head-major bias                                  @ 1179648 (4608)
// attst: bf16, pre-swizzled att [1024 mb][6 s][16384 B]                 @ 1184256 (100663296)
// xbf  : bf16 fragment-ordered x [1024 mb][6 s][8 f][2 c][64 lanes x16B] -> lives in d_out
constexpr size_t kWbfOff = 0;
constexpr size_t kWosOff = 884736;
constexpr size_t kBrrOff = 1179648;
constexpr size_t kAttOff = 1184256;

// ================= kernel 0: prep (convert + reorder weights) =================
__global__ void prep(const float* __restrict__ w_in, const float* __restrict__ b_in,
                     const float* __restrict__ w_out,
                     char* __restrict__ wbf, char* __restrict__ wos,
                     float* __restrict__ brr)
{
    const int i = blockIdx.x * 256 + threadIdx.x;   // grid covers 73728 exactly
    if (i < 55296) {
        // wbf granule: [hp][s][f][c][lane]
        int hp = i / 9216, rem = i % 9216;
        int s = rem / 1536, t = rem % 1536;
        int f = t >> 7, rem2 = t & 127;
        int c = rem2 >> 6, lane = rem2 & 63;
        int g = lane >> 4, r16 = lane & 15;
        int row = f * 16 + r16;                      // 0..191
        int hh = row / 96, rr = row % 96;
        int sec = rr >> 5, d = rr & 31;
        int srow = sec * 384 + (hp * 2 + hh) * 32 + d;
        int k0 = s * 64 + c * 32 + g * 8;
        const float4* src = (const float4*)(w_in + (size_t)srow * 384 + k0);
        float4 a = src[0], b = src[1];
        uint4 w;
        w.x = f2bf(a.x) | ((unsigned)f2bf(a.y) << 16);
        w.y = f2bf(a.z) | ((unsigned)f2bf(a.w) << 16);
        w.z = f2bf(b.x) | ((unsigned)f2bf(b.y) << 16);
        w.w = f2bf(b.z) | ((unsigned)f2bf(b.w) << 16);
        *(uint4*)(wbf + (size_t)i * 16) = w;
    } else {
        int j = i - 55296;                           // [0, 18432)
        int nb = j / 6144, rem = j % 6144;
        int s = rem / 1024, slot16 = rem % 1024;
        int row = slot16 >> 3, sl = slot16 & 7;
        int c8 = sl ^ (row & 7);
        int srow = nb * 128 + row;
        int k0 = s * 64 + c8 * 8;
        const float4* src = (const float4*)(w_out + (size_t)srow * 384 + k0);
        float4 a = src[0], b = src[1];
        uint4 w;
        w.x = f2bf(a.x) | ((unsigned)f2bf(a.y) << 16);
        w.y = f2bf(a.z) | ((unsigned)f2bf(a.w) << 16);
        w.z = f2bf(b.x) | ((unsigned)f2bf(b.y) << 16);
        w.w = f2bf(b.z) | ((unsigned)f2bf(b.w) << 16);
        *(uint4*)(wos + (size_t)j * 16) = w;
    }
    if (i < 1152) {
        int h = i / 96, jj = i % 96;
        int sec = jj >> 5, d = jj & 31;
        brr[i] = b_in[sec * 384 + h * 32 + d];
    }
}

// ================= kernel 0b: prep_x — x (f32) -> MFMA-fragment-ordered bf16 ====
__global__ void prep_x(const float* __restrict__ x, char* __restrict__ xbf)
{
    const int i = blockIdx.x * 256 + threadIdx.x;    // grid covers 6291456 exactly
    const int lane = i & 63;
    const int cc = (i >> 6) & 1;
    const int f = (i >> 7) & 7;
    const int rem = i >> 10;                          // mb*6 + s
    const int s = rem % 6, mb = rem / 6;

    int T = mb * 128 + f * 16 + (lane & 15);
    int win = T >> 4, t4 = T & 15;
    int bb = win >> 8, wh = (win >> 4) & 15, ww = win & 15;
    int n = (wh * 4 + (t4 >> 2)) * 64 + ww * 4 + (t4 & 3);
    int k0 = s * 64 + cc * 32 + (lane >> 4) * 8;

    const float4* src = (const float4*)(x + ((size_t)bb * 4096 + n) * 384 + k0);
    float4 a = src[0], b = src[1];
    uint4 w;
    w.x = f2bf(a.x) | ((unsigned)f2bf(a.y) << 16);
    w.y = f2bf(a.z) | ((unsigned)f2bf(a.w) << 16);
    w.z = f2bf(b.x) | ((unsigned)f2bf(b.y) << 16);
    w.w = f2bf(b.z) | ((unsigned)f2bf(b.w) << 16);
    *(uint4*)(xbf + (size_t)i * 16) = w;
}

// ================= kernel A: QKV projection + window attention =================
// grid: 1024 m-blocks x 6 head-pairs = 6144. block = 512 thr (8 waves).
// BM=128, BN=192, BK=64. Wave split 8x1: wave wid = M-frag wid (16 tokens), full N.
// GEMM phase: ALL operands from global (xbf + wbf, both fragment-ordered,
// L1/L2-hot). NO LDS, NO DMA, barriers only as cheap wave-pacing (L1 locality).
// Tail: wave-private LDS tiles [8 win][2 head]{Q|K|V 1K each} = 48KB.
__global__ __launch_bounds__(512, 2)
void qkv_attn(const char* __restrict__ xbf, const char* __restrict__ wbf,
              const float* __restrict__ brr, char* __restrict__ attst)
{
    __shared__ __align__(16) char smem[49152];

    const int tid  = threadIdx.x;
    const int lane = tid & 63, wid = tid >> 6;         // 8 waves = 8 M-frags
    const int g = lane >> 4, r16 = lane & 15;

    // hp-major within each XCD: co-resident blocks share the weight slice.
    int b = blockIdx.x;
    int x8 = b & 7, j = b >> 3;                        // j 0..767
    const int hp = j >> 7;                             // 0..5
    const int mblk = x8 * 128 + (j & 127);             // 0..1023

    const char* xw = xbf + (size_t)mblk * 98304 + (size_t)wid * 2048 + lane * 16;
    const char* bw = wbf + (size_t)hp * 147456 + lane * 16;

    f32x4 acc[12] = {};

    #pragma unroll
    for (int s = 0; s < 6; ++s) {
        __syncthreads();                               // pacing only (no LDS yet)
        short8 a[2];
        #pragma unroll
        for (int c = 0; c < 2; ++c)
            a[c] = *(const short8*)(xw + s * 16384 + c * 1024);
        #pragma unroll
        for (int c = 0; c < 2; ++c) {
            const char* bs = bw + s * 24576 + c * 1024;
            #pragma unroll
            for (int nh = 0; nh < 2; ++nh) {           // 6 frags at a time (VGPR cap)
                short8 bf[6];
                #pragma unroll
                for (int k = 0; k < 6; ++k)
                    bf[k] = *(const short8*)(bs + (nh * 6 + k) * 2048);
                #pragma unroll
                for (int k = 0; k < 6; ++k)
                    acc[nh * 6 + k] = MFMA16(a[c], bf[k], acc[nh * 6 + k]);
            }
        }
    }
    // no barrier: LDS tiles below are strictly wave-private

    // ---- epilogue: acc (+bias) -> Q^T/K^T/V^T tiles [d][t] for window wid ----
    char* tile = smem + wid * 6144;
    #pragma unroll
    for (int ni = 0; ni < 12; ++ni) {
        const int cb = ni * 16;                        // col base in [0,192)
        const int hl = cb / 96;                        // head-local 0/1
        const int w96 = cb - hl * 96;
        const int sec = w96 >> 5;                      // 0=Q 1=K 2=V
        const int d = (w96 & 31) + r16;
        const float bias = brr[(hp * 2 + hl) * 96 + w96 + r16];
        float v0 = acc[ni][0] + bias;
        float v1 = acc[ni][1] + bias;
        float v2 = acc[ni][2] + bias;
        float v3 = acc[ni][3] + bias;
        uint2 w;
        w.x = f2bf(v0) | ((unsigned)f2bf(v1) << 16);
        w.y = f2bf(v2) | ((unsigned)f2bf(v3) << 16);
        *(uint2*)(tile + hl * 3072 + sec * 1024 + d * 32 + g * 8) = w;
    }

    // ---- attention: wave wid owns window wid, loops over its 2 heads ----
    const float kC = 0.17677669529663687f * 1.4426950408889634f;  // (1/sqrt32)*log2e
    const f32x4 zero = {0.f, 0.f, 0.f, 0.f};
    const int win = wid;
    #pragma unroll
    for (int hl = 0; hl < 2; ++hl) {
        char* base = tile + hl * 3072;

        union U8 { unsigned short e[8]; short8 v; };
        U8 ku, qu;
        #pragma unroll
        for (int jj = 0; jj < 8; ++jj) {
            const int off = (g * 8 + jj) * 32 + r16 * 2;   // elem (d, t=r16)
            qu.e[jj] = *(const unsigned short*)(base + off);
            ku.e[jj] = *(const unsigned short*)(base + 1024 + off);
        }
        f32x4 s = MFMA16(ku.v, qu.v, zero);     // D[key=4g+r][q=r16]

        float m = fmaxf(fmaxf(s[0], s[1]), fmaxf(s[2], s[3]));
        m = fmaxf(m, __shfl_xor(m, 16, 64));
        m = fmaxf(m, __shfl_xor(m, 32, 64));
        float p[4], sum = 0.f;
        #pragma unroll
        for (int r = 0; r < 4; ++r) { p[r] = exp2f((s[r] - m) * kC); sum += p[r]; }
        sum += __shfl_xor(sum, 16, 64);
        sum += __shfl_xor(sum, 32, 64);
        const float inv = 1.f / sum;

        // P as in-register A-fragment under k-perm k=4g+j (upper 4 elems zero);
        // V's B-fragment uses the SAME key permutation.
        U8 pu;
        pu.e[0] = f2bf(p[0] * inv); pu.e[1] = f2bf(p[1] * inv);
        pu.e[2] = f2bf(p[2] * inv); pu.e[3] = f2bf(p[3] * inv);
        pu.e[4] = 0; pu.e[5] = 0; pu.e[6] = 0; pu.e[7] = 0;

        f32x4 o[2];
        #pragma unroll
        for (int ti = 0; ti < 2; ++ti) {
            U8 vu;                               // V[key=4g+j][d=ti*16+r16]
            *(uint2*)&vu.e[0] = *(const uint2*)(base + 2048 + (ti * 16 + r16) * 32 + g * 8);
            vu.e[4] = 0; vu.e[5] = 0; vu.e[6] = 0; vu.e[7] = 0;
            o[ti] = MFMA16(pu.v, vu.v, zero);    // D[q=4g+r][d-col=r16]
        }

        // transpose o via own tile's (now dead) Q/K area -> [t][64B] rows,
        // then ONE uint4 global store per lane into attst's granule layout.
        #pragma unroll
        for (int ti = 0; ti < 2; ++ti)
            #pragma unroll
            for (int r = 0; r < 4; ++r)
                *(unsigned short*)(base + (g * 4 + r) * 64 + (ti * 16 + r16) * 2)
                    = f2bf(o[ti][r]);
        uint4 ov = *(const uint4*)(base + r16 * 64 + g * 16);  // same-wave RAW

        const int ghead = hp * 2 + hl;
        int row7 = win * 16 + r16;               // row within this mblk (BM=128)
        int col8 = ghead * 4 + g;                // 16B-granule column index
        int sst = col8 >> 3;
        int sl = (col8 & 7) ^ (row7 & 7);
        *(uint4*)(attst + (size_t)mblk * 98304 + sst * 16384 + row7 * 128 + sl * 16) = ov;
    }
}

// ================= kernel B: out projection =================
// grid: 1024 m-blocks x 3 n-blocks = 3072. BM=128, BN=128, BK=64.
__global__ __launch_bounds__(256, 2)
void out_proj(const char* __restrict__ attst, const char* __restrict__ wos,
              const float* __restrict__ b_out, float* __restrict__ out)
{
    __shared__ __align__(16) char smem[65536];  // A 2x16K @0 ; B 2x16K @32768

    const int tid  = threadIdx.x;
    const int lane = tid & 63, wid = tid >> 6;
    const int g = lane >> 4, r16 = lane & 15;
    const int wm = wid >> 1, wn = wid & 1;

    int b = blockIdx.x;
    int L = (b & 7) * 384 + (b >> 3);
    const int mblk = L / 3, nblk = L - mblk * 3;

    auto stage = [&](int s, int buf) {
        const char* asrc = attst + (size_t)mblk * 98304 + s * 16384 + wid * 4096 + lane * 16;
        const char* bsrc = wos   + (size_t)nblk * 98304 + s * 16384 + wid * 4096 + lane * 16;
        char* adst = smem + buf * 16384 + wid * 4096;
        char* bdst = smem + 32768 + buf * 16384 + wid * 4096;
        #pragma unroll
        for (int j = 0; j < 4; ++j) {
            gload16(asrc + j * 1024, adst + j * 1024);
            gload16(bsrc + j * 1024, bdst + j * 1024);
        }
    };

    f32x4 acc[4][4] = {};
    auto compute = [&](int buf) {
        const char* ab = smem + buf * 16384;
        const char* bbp = smem + 32768 + buf * 16384;
        #pragma unroll
        for (int c = 0; c < 2; ++c) {
            const int sw = ((c * 4 + g) ^ (r16 & 7)) << 4;
            short8 a[4], bf[4];
            #pragma unroll
            for (int mi = 0; mi < 4; ++mi)
                a[mi] = *(const short8*)(ab + (wm * 64 + mi * 16 + r16) * 128 + sw);
            #pragma unroll
            for (int ni = 0; ni < 4; ++ni)
                bf[ni] = *(const short8*)(bbp + (wn * 64 + ni * 16 + r16) * 128 + sw);
            #pragma unroll
            for (int mi = 0; mi < 4; ++mi)
                #pragma unroll
                for (int ni = 0; ni < 4; ++ni)
                    acc[mi][ni] = MFMA16(a[mi], bf[ni], acc[mi][ni]);
        }
    };

    stage(0, 0);
    for (int s = 0; s < 6; ++s) {
        __syncthreads();
        if (s < 5) stage(s + 1, (s + 1) & 1);
        compute(s & 1);
    }

    float bias[4];
    #pragma unroll
    for (int ni = 0; ni < 4; ++ni) bias[ni] = b_out[nblk * 128 + wn * 64 + ni * 16 + r16];

    #pragma unroll
    for (int mi = 0; mi < 4; ++mi) {
        #pragma unroll
        for (int r = 0; r < 4; ++r) {
            int T = mblk * 128 + wm * 64 + mi * 16 + g * 4 + r;
            int win = T >> 4, tt = T & 15;
            int bb = win >> 8, wh = (win >> 4) & 15, ww = win & 15;
            size_t o = ((size_t)bb * 4096 + (wh * 4 + (tt >> 2)) * 64 + ww * 4 + (tt & 3)) * 384
                     + nblk * 128 + wn * 64;
            #pragma unroll
            for (int ni = 0; ni < 4; ++ni)
                out[o + ni * 16 + r16] = acc[mi][ni][r] + bias[ni];
        }
    }
}

extern "C" void kernel_launch(void* const* d_in, const int* in_sizes, int n_in,
                              void* d_out, int out_size, void* d_ws, size_t ws_size,
                              hipStream_t stream) {
    const float* x     = (const float*)d_in[0];
    const float* w_in  = (const float*)d_in[1];
    const float* b_in  = (const float*)d_in[2];
    const float* w_out = (const float*)d_in[3];
    const float* b_out = (const float*)d_in[4];
    float* out = (float*)d_out;

    char* ws = (char*)d_ws;
    char*  wbf = ws + kWbfOff;
    char*  wos = ws + kWosOff;
    float* brr = (float*)(ws + kBrrOff);
    char*  att = ws + kAttOff;
    // xbf scratch lives in d_out: written by prep_x, consumed by qkv_attn,
    // then fully overwritten by out_proj (stream-ordered, deterministic).
    char*  xbf = (char*)d_out;

    prep<<<dim3(288), dim3(256), 0, stream>>>(w_in, b_in, w_out, wbf, wos, brr);
    prep_x<<<dim3(24576), dim3(256), 0, stream>>>(x, xbf);
    qkv_attn<<<dim3(6144), dim3(512), 0, stream>>>(xbf, wbf, brr, att);
    out_proj<<<dim3(3072), dim3(256), 0, stream>>>(att, wos, b_out, out);
}

// Round 16
// 274.760 us; speedup vs baseline: 1.6399x; 1.6399x over previous
//
#include <hip/hip_runtime.h>
#include <hip/hip_bf16.h>

typedef __attribute__((ext_vector_type(8))) short short8;
typedef __attribute__((ext_vector_type(4))) float f32x4;

static __device__ __forceinline__ f32x4 MFMA16(short8 a, short8 b, f32x4 c) {
    return __builtin_amdgcn_mfma_f32_16x16x32_bf16(a, b, c, 0, 0, 0);
}
static __device__ __forceinline__ unsigned short f2bf(float f) {
    union { __hip_bfloat16 h; unsigned short u; } c;
    c.h = __float2bfloat16(f);
    return c.u;
}
static __device__ __forceinline__ void gload16(const void* g, void* l) {
    __builtin_amdgcn_global_load_lds(
        (const __attribute__((address_space(1))) unsigned int*)g,
        (__attribute__((address_space(3))) unsigned int*)l, 16, 0, 0);
}

// ---------------- ws layout ----------------
// wst  : bf16, LDS-order pre-swizzled w_in, PER-HEAD: [12 h][6 s][768 gran x16B] @0 (884736)
//        granule(row 0..95, sl 0..7): k-octet c8 = sl ^ (row&7); row = sec*32 + d
// wos  : bf16, LDS-order pre-swizzled w_out [3 nb][6 s][1024 gran x16B] @ 884736 (294912)
// brr  : f32  [12][96] head-major bias                                  @ 1179648 (4608)
// attst: bf16, pre-swizzled att [1024 mb][6 s][16384 B]                 @ 1184256 (100663296)
// xbf  : bf16 fragment-ordered x [1024 mb][6 s][8 f][2 c][64 lanes x16B] -> lives in d_out
constexpr size_t kWstOff = 0;
constexpr size_t kWosOff = 884736;
constexpr size_t kBrrOff = 1179648;
constexpr size_t kAttOff = 1184256;

// ================= kernel 0: prep (convert + reorder weights) =================
__global__ void prep(const float* __restrict__ w_in, const float* __restrict__ b_in,
                     const float* __restrict__ w_out,
                     char* __restrict__ wst, char* __restrict__ wos,
                     float* __restrict__ brr)
{
    const int i = blockIdx.x * 256 + threadIdx.x;   // grid covers 73728 exactly
    if (i < 55296) {
        // wst granule: [h][s][row*8 + sl]
        int h = i / 4608, rem = i % 4608;
        int s = rem / 768, t = rem % 768;
        int row = t >> 3, sl = t & 7;
        int c8 = sl ^ (row & 7);
        int sec = row >> 5, d = row & 31;
        int srow = sec * 384 + h * 32 + d;
        int k0 = s * 64 + c8 * 8;
        const float4* src = (const float4*)(w_in + (size_t)srow * 384 + k0);
        float4 a = src[0], b = src[1];
        uint4 w;
        w.x = f2bf(a.x) | ((unsigned)f2bf(a.y) << 16);
        w.y = f2bf(a.z) | ((unsigned)f2bf(a.w) << 16);
        w.z = f2bf(b.x) | ((unsigned)f2bf(b.y) << 16);
        w.w = f2bf(b.z) | ((unsigned)f2bf(b.w) << 16);
        *(uint4*)(wst + (size_t)i * 16) = w;
    } else {
        int j = i - 55296;                           // [0, 18432)
        int nb = j / 6144, rem = j % 6144;
        int s = rem / 1024, slot16 = rem % 1024;
        int row = slot16 >> 3, sl = slot16 & 7;
        int c8 = sl ^ (row & 7);
        int srow = nb * 128 + row;
        int k0 = s * 64 + c8 * 8;
        const float4* src = (const float4*)(w_out + (size_t)srow * 384 + k0);
        float4 a = src[0], b = src[1];
        uint4 w;
        w.x = f2bf(a.x) | ((unsigned)f2bf(a.y) << 16);
        w.y = f2bf(a.z) | ((unsigned)f2bf(a.w) << 16);
        w.z = f2bf(b.x) | ((unsigned)f2bf(b.y) << 16);
        w.w = f2bf(b.z) | ((unsigned)f2bf(b.w) << 16);
        *(uint4*)(wos + (size_t)j * 16) = w;
    }
    if (i < 1152) {
        int h = i / 96, jj = i % 96;
        int sec = jj >> 5, d = jj & 31;
        brr[i] = b_in[sec * 384 + h * 32 + d];
    }
}

// ================= kernel 0b: prep_x — x (f32) -> MFMA-fragment-ordered bf16 ====
__global__ void prep_x(const float* __restrict__ x, char* __restrict__ xbf)
{
    const int i = blockIdx.x * 256 + threadIdx.x;    // grid covers 6291456 exactly
    const int lane = i & 63;
    const int cc = (i >> 6) & 1;
    const int f = (i >> 7) & 7;
    const int rem = i >> 10;                          // mb*6 + s
    const int s = rem % 6, mb = rem / 6;

    int T = mb * 128 + f * 16 + (lane & 15);
    int win = T >> 4, t4 = T & 15;
    int bb = win >> 8, wh = (win >> 4) & 15, ww = win & 15;
    int n = (wh * 4 + (t4 >> 2)) * 64 + ww * 4 + (t4 & 3);
    int k0 = s * 64 + cc * 32 + (lane >> 4) * 8;

    const float4* src = (const float4*)(x + ((size_t)bb * 4096 + n) * 384 + k0);
    float4 a = src[0], b = src[1];
    uint4 w;
    w.x = f2bf(a.x) | ((unsigned)f2bf(a.y) << 16);
    w.y = f2bf(a.z) | ((unsigned)f2bf(a.w) << 16);
    w.z = f2bf(b.x) | ((unsigned)f2bf(b.y) << 16);
    w.w = f2bf(b.z) | ((unsigned)f2bf(b.w) << 16);
    *(uint4*)(xbf + (size_t)i * 16) = w;
}

// ================= kernel A: QKV projection + window attention =================
// grid: 1024 m-blocks x 12 heads = 12288. block = 512 thr (8 waves).
// BM=128, BN=96 (one head: q32|k32|v32), BK=64. Wave = 1 M-frag x full N -> acc[6].
// A: fragment loads from xbf (global, L2-hot), issued BEFORE the B DMA
//    (issue-order vmcnt trick, r13-proven). B: gload16 dbuf LDS, 1 barrier/step.
// LDS 48KB: B 2x12KB @0 ; tail tiles [8 win]{Q|K|V 1K} @24576 (no aliasing ->
// ZERO barriers after the loop). Target 3 blocks/CU = 6 waves/SIMD.
__global__ __launch_bounds__(512, 6)
void qkv_attn(const char* __restrict__ xbf, const char* __restrict__ wst,
              const float* __restrict__ brr, char* __restrict__ attst)
{
    __shared__ __align__(16) char smem[49152];

    const int tid  = threadIdx.x;
    const int lane = tid & 63, wid = tid >> 6;         // 8 waves = 8 M-frags
    const int g = lane >> 4, r16 = lane & 15;

    // head-fastest grouping within each XCD: 96 co-resident blocks/XCD share
    // 8 xbf slices (768KB) + all 12 head W slices (864KB) in L2.
    int b = blockIdx.x;
    int x8 = b & 7, j = b >> 3;                        // j 0..1535
    const int head = j % 12;
    const int mblk = x8 * 128 + j / 12;                // 0..1023

    const char* xw = xbf + (size_t)mblk * 98304 + (size_t)wid * 2048 + lane * 16;
    const char* whp = wst + (size_t)head * 73728;

    auto stage_B = [&](int s, int buf) {
        char* dst = smem + buf * 12288;
        const char* src = whp + s * 12288;
        gload16(src + tid * 16, dst + tid * 16);
        if (tid < 256) gload16(src + 8192 + tid * 16, dst + 8192 + tid * 16);
    };

    f32x4 acc[6] = {};

    // main loop: ONE barrier/step; A-loads oldest, DMA newest (vmcnt ordering).
    stage_B(0, 0);
    for (int s = 0; s < 6; ++s) {
        __syncthreads();                       // B(s) DMA drained
        short8 a[2];
        a[0] = *(const short8*)(xw + s * 16384);
        a[1] = *(const short8*)(xw + s * 16384 + 1024);
        __builtin_amdgcn_sched_barrier(0);     // pin: DMA issues AFTER A-loads
        if (s < 5) stage_B(s + 1, (s + 1) & 1);

        const char* bbp = smem + (s & 1) * 12288;
        #pragma unroll
        for (int c = 0; c < 2; ++c) {
            const int sw = ((c * 4 + g) ^ (r16 & 7)) << 4;
            #pragma unroll
            for (int nh = 0; nh < 2; ++nh) {   // 3 B-frags at a time (VGPR cap)
                short8 bf[3];
                #pragma unroll
                for (int k = 0; k < 3; ++k)
                    bf[k] = *(const short8*)(bbp + ((nh * 3 + k) * 16 + r16) * 128 + sw);
                #pragma unroll
                for (int k = 0; k < 3; ++k)
                    acc[nh * 3 + k] = MFMA16(a[c], bf[k], acc[nh * 3 + k]);
            }
        }
    }
    // tail tiles (@24576) don't alias B buffers and are wave-private: NO barrier.

    // ---- epilogue: acc (+bias) -> Q^T/K^T/V^T tiles [d][t] for window wid ----
    char* tile = smem + 24576 + wid * 3072;
    #pragma unroll
    for (int ni = 0; ni < 6; ++ni) {
        const int sec = ni >> 1;                       // 0=Q 1=K 2=V
        const int d = (ni & 1) * 16 + r16;
        const float bias = brr[head * 96 + ni * 16 + r16];
        float v0 = acc[ni][0] + bias;
        float v1 = acc[ni][1] + bias;
        float v2 = acc[ni][2] + bias;
        float v3 = acc[ni][3] + bias;
        uint2 w;
        w.x = f2bf(v0) | ((unsigned)f2bf(v1) << 16);
        w.y = f2bf(v2) | ((unsigned)f2bf(v3) << 16);
        *(uint2*)(tile + sec * 1024 + d * 32 + g * 8) = w;
    }

    // ---- attention: one (window wid, head) per wave, zero barriers ----
    const float kC = 0.17677669529663687f * 1.4426950408889634f;  // (1/sqrt32)*log2e
    const f32x4 zero = {0.f, 0.f, 0.f, 0.f};

    union U8 { unsigned short e[8]; short8 v; };
    U8 ku, qu;
    #pragma unroll
    for (int jj = 0; jj < 8; ++jj) {
        const int off = (g * 8 + jj) * 32 + r16 * 2;   // elem (d, t=r16)
        qu.e[jj] = *(const unsigned short*)(tile + off);
        ku.e[jj] = *(const unsigned short*)(tile + 1024 + off);
    }
    f32x4 s = MFMA16(ku.v, qu.v, zero);         // D[key=4g+r][q=r16]

    float m = fmaxf(fmaxf(s[0], s[1]), fmaxf(s[2], s[3]));
    m = fmaxf(m, __shfl_xor(m, 16, 64));
    m = fmaxf(m, __shfl_xor(m, 32, 64));
    float p[4], sum = 0.f;
    #pragma unroll
    for (int r = 0; r < 4; ++r) { p[r] = exp2f((s[r] - m) * kC); sum += p[r]; }
    sum += __shfl_xor(sum, 16, 64);
    sum += __shfl_xor(sum, 32, 64);
    const float inv = 1.f / sum;

    // P as in-register A-fragment under k-perm k=4g+j (upper 4 elems zero);
    // V's B-fragment uses the SAME key permutation.
    U8 pu;
    pu.e[0] = f2bf(p[0] * inv); pu.e[1] = f2bf(p[1] * inv);
    pu.e[2] = f2bf(p[2] * inv); pu.e[3] = f2bf(p[3] * inv);
    pu.e[4] = 0; pu.e[5] = 0; pu.e[6] = 0; pu.e[7] = 0;

    f32x4 o[2];
    #pragma unroll
    for (int ti = 0; ti < 2; ++ti) {
        U8 vu;                                   // V[key=4g+j][d=ti*16+r16]
        *(uint2*)&vu.e[0] = *(const uint2*)(tile + 2048 + (ti * 16 + r16) * 32 + g * 8);
        vu.e[4] = 0; vu.e[5] = 0; vu.e[6] = 0; vu.e[7] = 0;
        o[ti] = MFMA16(pu.v, vu.v, zero);        // D[q=4g+r][d-col=r16]
    }

    // transpose o via own tile's (now dead) Q area -> [t][64B] rows,
    // then ONE uint4 global store per lane into attst's granule layout.
    #pragma unroll
    for (int ti = 0; ti < 2; ++ti)
        #pragma unroll
        for (int r = 0; r < 4; ++r)
            *(unsigned short*)(tile + (g * 4 + r) * 64 + (ti * 16 + r16) * 2)
                = f2bf(o[ti][r]);
    uint4 ov = *(const uint4*)(tile + r16 * 64 + g * 16);  // same-wave RAW

    int row7 = wid * 16 + r16;                   // row within this mblk (BM=128)
    int col8 = head * 4 + g;                     // 16B-granule column index
    int sst = col8 >> 3;
    int sl = (col8 & 7) ^ (row7 & 7);
    *(uint4*)(attst + (size_t)mblk * 98304 + sst * 16384 + row7 * 128 + sl * 16) = ov;
}

// ================= kernel B: out projection =================
// grid: 1024 m-blocks x 3 n-blocks = 3072. BM=128, BN=128, BK=64.
__global__ __launch_bounds__(256, 2)
void out_proj(const char* __restrict__ attst, const char* __restrict__ wos,
              const float* __restrict__ b_out, float* __restrict__ out)
{
    __shared__ __align__(16) char smem[65536];  // A 2x16K @0 ; B 2x16K @32768

    const int tid  = threadIdx.x;
    const int lane = tid & 63, wid = tid >> 6;
    const int g = lane >> 4, r16 = lane & 15;
    const int wm = wid >> 1, wn = wid & 1;

    int b = blockIdx.x;
    int L = (b & 7) * 384 + (b >> 3);
    const int mblk = L / 3, nblk = L - mblk * 3;

    auto stage = [&](int s, int buf) {
        const char* asrc = attst + (size_t)mblk * 98304 + s * 16384 + wid * 4096 + lane * 16;
        const char* bsrc = wos   + (size_t)nblk * 98304 + s * 16384 + wid * 4096 + lane * 16;
        char* adst = smem + buf * 16384 + wid * 4096;
        char* bdst = smem + 32768 + buf * 16384 + wid * 4096;
        #pragma unroll
        for (int j = 0; j < 4; ++j) {
            gload16(asrc + j * 1024, adst + j * 1024);
            gload16(bsrc + j * 1024, bdst + j * 1024);
        }
    };

    f32x4 acc[4][4] = {};
    auto compute = [&](int buf) {
        const char* ab = smem + buf * 16384;
        const char* bbp = smem + 32768 + buf * 16384;
        #pragma unroll
        for (int c = 0; c < 2; ++c) {
            const int sw = ((c * 4 + g) ^ (r16 & 7)) << 4;
            short8 a[4], bf[4];
            #pragma unroll
            for (int mi = 0; mi < 4; ++mi)
                a[mi] = *(const short8*)(ab + (wm * 64 + mi * 16 + r16) * 128 + sw);
            #pragma unroll
            for (int ni = 0; ni < 4; ++ni)
                bf[ni] = *(const short8*)(bbp + (wn * 64 + ni * 16 + r16) * 128 + sw);
            #pragma unroll
            for (int mi = 0; mi < 4; ++mi)
                #pragma unroll
                for (int ni = 0; ni < 4; ++ni)
                    acc[mi][ni] = MFMA16(a[mi], bf[ni], acc[mi][ni]);
        }
    };

    stage(0, 0);
    for (int s = 0; s < 6; ++s) {
        __syncthreads();
        if (s < 5) stage(s + 1, (s + 1) & 1);
        compute(s & 1);
    }

    float bias[4];
    #pragma unroll
    for (int ni = 0; ni < 4; ++ni) bias[ni] = b_out[nblk * 128 + wn * 64 + ni * 16 + r16];

    #pragma unroll
    for (int mi = 0; mi < 4; ++mi) {
        #pragma unroll
        for (int r = 0; r < 4; ++r) {
            int T = mblk * 128 + wm * 64 + mi * 16 + g * 4 + r;
            int win = T >> 4, tt = T & 15;
            int bb = win >> 8, wh = (win >> 4) & 15, ww = win & 15;
            size_t o = ((size_t)bb * 4096 + (wh * 4 + (tt >> 2)) * 64 + ww * 4 + (tt & 3)) * 384
                     + nblk * 128 + wn * 64;
            #pragma unroll
            for (int ni = 0; ni < 4; ++ni)
                out[o + ni * 16 + r16] = acc[mi][ni][r] + bias[ni];
        }
    }
}

extern "C" void kernel_launch(void* const* d_in, const int* in_sizes, int n_in,
                              void* d_out, int out_size, void* d_ws, size_t ws_size,
                              hipStream_t stream) {
    const float* x     = (const float*)d_in[0];
    const float* w_in  = (const float*)d_in[1];
    const float* b_in  = (const float*)d_in[2];
    const float* w_out = (const float*)d_in[3];
    const float* b_out = (const float*)d_in[4];
    float* out = (float*)d_out;

    char* ws = (char*)d_ws;
    char*  wst = ws + kWstOff;
    char*  wos = ws + kWosOff;
    float* brr = (float*)(ws + kBrrOff);
    char*  att = ws + kAttOff;
    // xbf scratch lives in d_out: written by prep_x, consumed by qkv_attn,
    // then fully overwritten by out_proj (stream-ordered, deterministic).
    char*  xbf = (char*)d_out;

    prep<<<dim3(288), dim3(256), 0, stream>>>(w_in, b_in, w_out, wst, wos, brr);
    prep_x<<<dim3(24576), dim3(256), 0, stream>>>(x, xbf);
    qkv_attn<<<dim3(12288), dim3(512), 0, stream>>>(xbf, wst, brr, att);
    out_proj<<<dim3(3072), dim3(256), 0, stream>>>(att, wos, b_out, out);
}

// Round 17
// 272.946 us; speedup vs baseline: 1.6508x; 1.0066x over previous
//
#include <hip/hip_runtime.h>
#include <hip/hip_bf16.h>

typedef __attribute__((ext_vector_type(8))) short short8;
typedef __attribute__((ext_vector_type(4))) float f32x4;

static __device__ __forceinline__ f32x4 MFMA16(short8 a, short8 b, f32x4 c) {
    return __builtin_amdgcn_mfma_f32_16x16x32_bf16(a, b, c, 0, 0, 0);
}
static __device__ __forceinline__ unsigned short f2bf(float f) {
    union { __hip_bfloat16 h; unsigned short u; } c;
    c.h = __float2bfloat16(f);
    return c.u;
}
static __device__ __forceinline__ void gload16(const void* g, void* l) {
    __builtin_amdgcn_global_load_lds(
        (const __attribute__((address_space(1))) unsigned int*)g,
        (__attribute__((address_space(3))) unsigned int*)l, 16, 0, 0);
}

// ---------------- ws layout ----------------
// wst  : bf16, LDS-order pre-swizzled w_in, PER-HEAD: [12 h][6 s][768 gran x16B] @0 (884736)
// wos  : bf16, LDS-order pre-swizzled w_out [3 nb][6 s][1024 gran x16B] @ 884736 (294912)
// brr  : f32  [12][96] head-major bias                                  @ 1179648 (4608)
// attst: bf16, pre-swizzled att [1024 mb][6 s][16384 B]                 @ 1184256 (100663296)
// xbf  : bf16 fragment-ordered x [1024 mb][6 s][8 f][2 c][64 lanes x16B] -> lives in d_out
constexpr size_t kWstOff = 0;
constexpr size_t kWosOff = 884736;
constexpr size_t kBrrOff = 1179648;
constexpr size_t kAttOff = 1184256;

// ================= kernel 0: prep (convert + reorder weights) =================
__global__ void prep(const float* __restrict__ w_in, const float* __restrict__ b_in,
                     const float* __restrict__ w_out,
                     char* __restrict__ wst, char* __restrict__ wos,
                     float* __restrict__ brr)
{
    const int i = blockIdx.x * 256 + threadIdx.x;   // grid covers 73728 exactly
    if (i < 55296) {
        int h = i / 4608, rem = i % 4608;
        int s = rem / 768, t = rem % 768;
        int row = t >> 3, sl = t & 7;
        int c8 = sl ^ (row & 7);
        int sec = row >> 5, d = row & 31;
        int srow = sec * 384 + h * 32 + d;
        int k0 = s * 64 + c8 * 8;
        const float4* src = (const float4*)(w_in + (size_t)srow * 384 + k0);
        float4 a = src[0], b = src[1];
        uint4 w;
        w.x = f2bf(a.x) | ((unsigned)f2bf(a.y) << 16);
        w.y = f2bf(a.z) | ((unsigned)f2bf(a.w) << 16);
        w.z = f2bf(b.x) | ((unsigned)f2bf(b.y) << 16);
        w.w = f2bf(b.z) | ((unsigned)f2bf(b.w) << 16);
        *(uint4*)(wst + (size_t)i * 16) = w;
    } else {
        int j = i - 55296;                           // [0, 18432)
        int nb = j / 6144, rem = j % 6144;
        int s = rem / 1024, slot16 = rem % 1024;
        int row = slot16 >> 3, sl = slot16 & 7;
        int c8 = sl ^ (row & 7);
        int srow = nb * 128 + row;
        int k0 = s * 64 + c8 * 8;
        const float4* src = (const float4*)(w_out + (size_t)srow * 384 + k0);
        float4 a = src[0], b = src[1];
        uint4 w;
        w.x = f2bf(a.x) | ((unsigned)f2bf(a.y) << 16);
        w.y = f2bf(a.z) | ((unsigned)f2bf(a.w) << 16);
        w.z = f2bf(b.x) | ((unsigned)f2bf(b.y) << 16);
        w.w = f2bf(b.z) | ((unsigned)f2bf(b.w) << 16);
        *(uint4*)(wos + (size_t)j * 16) = w;
    }
    if (i < 1152) {
        int h = i / 96, jj = i % 96;
        int sec = jj >> 5, d = jj & 31;
        brr[i] = b_in[sec * 384 + h * 32 + d];
    }
}

// ================= kernel 0b: prep_x — x (f32) -> MFMA-fragment-ordered bf16 ====
__global__ void prep_x(const float* __restrict__ x, char* __restrict__ xbf)
{
    const int i = blockIdx.x * 256 + threadIdx.x;    // grid covers 6291456 exactly
    const int lane = i & 63;
    const int cc = (i >> 6) & 1;
    const int f = (i >> 7) & 7;
    const int rem = i >> 10;                          // mb*6 + s
    const int s = rem % 6, mb = rem / 6;

    int T = mb * 128 + f * 16 + (lane & 15);
    int win = T >> 4, t4 = T & 15;
    int bb = win >> 8, wh = (win >> 4) & 15, ww = win & 15;
    int n = (wh * 4 + (t4 >> 2)) * 64 + ww * 4 + (t4 & 3);
    int k0 = s * 64 + cc * 32 + (lane >> 4) * 8;

    const float4* src = (const float4*)(x + ((size_t)bb * 4096 + n) * 384 + k0);
    float4 a = src[0], b = src[1];
    uint4 w;
    w.x = f2bf(a.x) | ((unsigned)f2bf(a.y) << 16);
    w.y = f2bf(a.z) | ((unsigned)f2bf(a.w) << 16);
    w.z = f2bf(b.x) | ((unsigned)f2bf(b.y) << 16);
    w.w = f2bf(b.z) | ((unsigned)f2bf(b.w) << 16);
    *(uint4*)(xbf + (size_t)i * 16) = w;
}

// ================= kernel A: QKV projection + window attention =================
// grid: 1024 m-blocks x 12 heads = 12288. block = 512 thr (8 waves).
// BM=128, BN=96 (one head), BK=64. Wave = 1 M-frag x full N -> acc[6].
// Counted-vmcnt triple-buffer pipeline (T3+T4): B DMA lookahead 2, raw s_barrier,
// NEVER vmcnt(0) in the loop body; A(s+1) reg-prefetched BEFORE the DMA issue so
// the counted wait covers it. LDS 36KB: B 3x12KB; tail tiles alias bufs 0/1
// (step 5 reads buf 2 only; steps<=4 closed by barrier) -> zero extra barriers.
__global__ __launch_bounds__(512, 6)
void qkv_attn(const char* __restrict__ xbf, const char* __restrict__ wst,
              const float* __restrict__ brr, char* __restrict__ attst)
{
    __shared__ __align__(16) char smem[36864];

    const int tid  = threadIdx.x;
    const int lane = tid & 63, wid = tid >> 6;         // 8 waves = 8 M-frags
    const int g = lane >> 4, r16 = lane & 15;

    // head-fastest grouping within each XCD (L2: 8 xbf slices + 12 W slices)
    int b = blockIdx.x;
    int x8 = b & 7, j = b >> 3;                        // j 0..1535
    const int head = j % 12;
    const int mblk = x8 * 128 + j / 12;                // 0..1023

    const char* xw = xbf + (size_t)mblk * 98304 + (size_t)wid * 2048 + lane * 16;
    const char* whp = wst + (size_t)head * 73728;

    // 768 granules per B tile; waves 0..5 carry 2 DMA ops each, waves 6..7 none.
    auto stage_B = [&](int s, int buf) {
        if (tid < 384) {
            char* dst = smem + buf * 12288 + tid * 16;
            const char* src = whp + s * 12288 + tid * 16;
            gload16(src, dst);
            gload16(src + 6144, dst + 6144);
        }
    };

    f32x4 acc[6] = {};
    short8 acur0, acur1, anext0, anext1;

    // prologue issue order (oldest->newest): B0 DMA, A0 loads, B1 DMA
    stage_B(0, 0);
    acur0 = *(const short8*)(xw);
    acur1 = *(const short8*)(xw + 1024);
    stage_B(1, 1);

    #pragma unroll
    for (int s = 0; s < 6; ++s) {
        // counted wait: drain through A(s)+B(s), keep B(s+1) in flight
        __builtin_amdgcn_sched_barrier(0);
        if (s < 5 && wid < 6) {
            asm volatile("s_waitcnt vmcnt(2)" ::: "memory");
        } else {
            asm volatile("s_waitcnt vmcnt(0)" ::: "memory");
        }
        __builtin_amdgcn_sched_barrier(0);
        __builtin_amdgcn_s_barrier();                  // raw: no compiler drain
        __builtin_amdgcn_sched_barrier(0);

        if (s < 5) {
            anext0 = *(const short8*)(xw + (s + 1) * 16384);
            anext1 = *(const short8*)(xw + (s + 1) * 16384 + 1024);
        }
        if (s < 4) stage_B(s + 2, (s + 2) % 3);        // overwrites buf (s-1)%3: safe

        const char* bbp = smem + (s % 3) * 12288;
        #pragma unroll
        for (int c = 0; c < 2; ++c) {
            const int sw = ((c * 4 + g) ^ (r16 & 7)) << 4;
            const short8 ac = (c == 0) ? acur0 : acur1;
            #pragma unroll
            for (int nh = 0; nh < 2; ++nh) {
                short8 bf[3];
                #pragma unroll
                for (int k = 0; k < 3; ++k)
                    bf[k] = *(const short8*)(bbp + ((nh * 3 + k) * 16 + r16) * 128 + sw);
                #pragma unroll
                for (int k = 0; k < 3; ++k)
                    acc[nh * 3 + k] = MFMA16(ac, bf[k], acc[nh * 3 + k]);
            }
        }
        acur0 = anext0;
        acur1 = anext1;
    }
    // tail tiles (@0..24576 = bufs 0/1) vs step-5 reads (buf 2): disjoint.
    // steps <=4 reads closed by barrier(5). Wave-private tiles: NO barrier.

    // ---- epilogue: acc (+bias) -> Q^T/K^T/V^T tiles [d][t] for window wid ----
    char* tile = smem + wid * 3072;
    #pragma unroll
    for (int ni = 0; ni < 6; ++ni) {
        const int sec = ni >> 1;                       // 0=Q 1=K 2=V
        const int d = (ni & 1) * 16 + r16;
        const float bias = brr[head * 96 + ni * 16 + r16];
        float v0 = acc[ni][0] + bias;
        float v1 = acc[ni][1] + bias;
        float v2 = acc[ni][2] + bias;
        float v3 = acc[ni][3] + bias;
        uint2 w;
        w.x = f2bf(v0) | ((unsigned)f2bf(v1) << 16);
        w.y = f2bf(v2) | ((unsigned)f2bf(v3) << 16);
        *(uint2*)(tile + sec * 1024 + d * 32 + g * 8) = w;
    }

    // ---- attention: one (window wid, head) per wave, zero barriers ----
    const float kC = 0.17677669529663687f * 1.4426950408889634f;  // (1/sqrt32)*log2e
    const f32x4 zero = {0.f, 0.f, 0.f, 0.f};

    union U8 { unsigned short e[8]; short8 v; };
    U8 ku, qu;
    #pragma unroll
    for (int jj = 0; jj < 8; ++jj) {
        const int off = (g * 8 + jj) * 32 + r16 * 2;   // elem (d, t=r16)
        qu.e[jj] = *(const unsigned short*)(tile + off);
        ku.e[jj] = *(const unsigned short*)(tile + 1024 + off);
    }
    f32x4 s = MFMA16(ku.v, qu.v, zero);         // D[key=4g+r][q=r16]

    float m = fmaxf(fmaxf(s[0], s[1]), fmaxf(s[2], s[3]));
    m = fmaxf(m, __shfl_xor(m, 16, 64));
    m = fmaxf(m, __shfl_xor(m, 32, 64));
    float p[4], sum = 0.f;
    #pragma unroll
    for (int r = 0; r < 4; ++r) { p[r] = exp2f((s[r] - m) * kC); sum += p[r]; }
    sum += __shfl_xor(sum, 16, 64);
    sum += __shfl_xor(sum, 32, 64);
    const float inv = 1.f / sum;

    // P as in-register A-fragment under k-perm k=4g+j (upper 4 elems zero);
    // V's B-fragment uses the SAME key permutation.
    U8 pu;
    pu.e[0] = f2bf(p[0] * inv); pu.e[1] = f2bf(p[1] * inv);
    pu.e[2] = f2bf(p[2] * inv); pu.e[3] = f2bf(p[3] * inv);
    pu.e[4] = 0; pu.e[5] = 0; pu.e[6] = 0; pu.e[7] = 0;

    f32x4 o[2];
    #pragma unroll
    for (int ti = 0; ti < 2; ++ti) {
        U8 vu;                                   // V[key=4g+j][d=ti*16+r16]
        *(uint2*)&vu.e[0] = *(const uint2*)(tile + 2048 + (ti * 16 + r16) * 32 + g * 8);
        vu.e[4] = 0; vu.e[5] = 0; vu.e[6] = 0; vu.e[7] = 0;
        o[ti] = MFMA16(pu.v, vu.v, zero);        // D[q=4g+r][d-col=r16]
    }

    // transpose o via own tile's (now dead) Q area -> [t][64B] rows,
    // then ONE uint4 global store per lane into attst's granule layout.
    #pragma unroll
    for (int ti = 0; ti < 2; ++ti)
        #pragma unroll
        for (int r = 0; r < 4; ++r)
            *(unsigned short*)(tile + (g * 4 + r) * 64 + (ti * 16 + r16) * 2)
                = f2bf(o[ti][r]);
    uint4 ov = *(const uint4*)(tile + r16 * 64 + g * 16);  // same-wave RAW

    int row7 = wid * 16 + r16;                   // row within this mblk (BM=128)
    int col8 = head * 4 + g;                     // 16B-granule column index
    int sst = col8 >> 3;
    int sl = (col8 & 7) ^ (row7 & 7);
    *(uint4*)(attst + (size_t)mblk * 98304 + sst * 16384 + row7 * 128 + sl * 16) = ov;
}

// ================= kernel B: out projection =================
// grid: 1024 m-blocks x 3 n-blocks = 3072. BM=128, BN=128, BK=64.
__global__ __launch_bounds__(256, 2)
void out_proj(const char* __restrict__ attst, const char* __restrict__ wos,
              const float* __restrict__ b_out, float* __restrict__ out)
{
    __shared__ __align__(16) char smem[65536];  // A 2x16K @0 ; B 2x16K @32768

    const int tid  = threadIdx.x;
    const int lane = tid & 63, wid = tid >> 6;
    const int g = lane >> 4, r16 = lane & 15;
    const int wm = wid >> 1, wn = wid & 1;

    int b = blockIdx.x;
    int L = (b & 7) * 384 + (b >> 3);
    const int mblk = L / 3, nblk = L - mblk * 3;

    auto stage = [&](int s, int buf) {
        const char* asrc = attst + (size_t)mblk * 98304 + s * 16384 + wid * 4096 + lane * 16;
        const char* bsrc = wos   + (size_t)nblk * 98304 + s * 16384 + wid * 4096 + lane * 16;
        char* adst = smem + buf * 16384 + wid * 4096;
        char* bdst = smem + 32768 + buf * 16384 + wid * 4096;
        #pragma unroll
        for (int j = 0; j < 4; ++j) {
            gload16(asrc + j * 1024, adst + j * 1024);
            gload16(bsrc + j * 1024, bdst + j * 1024);
        }
    };

    f32x4 acc[4][4] = {};
    auto compute = [&](int buf) {
        const char* ab = smem + buf * 16384;
        const char* bbp = smem + 32768 + buf * 16384;
        #pragma unroll
        for (int c = 0; c < 2; ++c) {
            const int sw = ((c * 4 + g) ^ (r16 & 7)) << 4;
            short8 a[4], bf[4];
            #pragma unroll
            for (int mi = 0; mi < 4; ++mi)
                a[mi] = *(const short8*)(ab + (wm * 64 + mi * 16 + r16) * 128 + sw);
            #pragma unroll
            for (int ni = 0; ni < 4; ++ni)
                bf[ni] = *(const short8*)(bbp + (wn * 64 + ni * 16 + r16) * 128 + sw);
            #pragma unroll
            for (int mi = 0; mi < 4; ++mi)
                #pragma unroll
                for (int ni = 0; ni < 4; ++ni)
                    acc[mi][ni] = MFMA16(a[mi], bf[ni], acc[mi][ni]);
        }
    };

    stage(0, 0);
    for (int s = 0; s < 6; ++s) {
        __syncthreads();
        if (s < 5) stage(s + 1, (s + 1) & 1);
        compute(s & 1);
    }

    float bias[4];
    #pragma unroll
    for (int ni = 0; ni < 4; ++ni) bias[ni] = b_out[nblk * 128 + wn * 64 + ni * 16 + r16];

    #pragma unroll
    for (int mi = 0; mi < 4; ++mi) {
        #pragma unroll
        for (int r = 0; r < 4; ++r) {
            int T = mblk * 128 + wm * 64 + mi * 16 + g * 4 + r;
            int win = T >> 4, tt = T & 15;
            int bb = win >> 8, wh = (win >> 4) & 15, ww = win & 15;
            size_t o = ((size_t)bb * 4096 + (wh * 4 + (tt >> 2)) * 64 + ww * 4 + (tt & 3)) * 384
                     + nblk * 128 + wn * 64;
            #pragma unroll
            for (int ni = 0; ni < 4; ++ni)
                out[o + ni * 16 + r16] = acc[mi][ni][r] + bias[ni];
        }
    }
}

extern "C" void kernel_launch(void* const* d_in, const int* in_sizes, int n_in,
                              void* d_out, int out_size, void* d_ws, size_t ws_size,
                              hipStream_t stream) {
    const float* x     = (const float*)d_in[0];
    const float* w_in  = (const float*)d_in[1];
    const float* b_in  = (const float*)d_in[2];
    const float* w_out = (const float*)d_in[3];
    const float* b_out = (const float*)d_in[4];
    float* out = (float*)d_out;

    char* ws = (char*)d_ws;
    char*  wst = ws + kWstOff;
    char*  wos = ws + kWosOff;
    float* brr = (float*)(ws + kBrrOff);
    char*  att = ws + kAttOff;
    // xbf scratch lives in d_out: written by prep_x, consumed by qkv_attn,
    // then fully overwritten by out_proj (stream-ordered, deterministic).
    char*  xbf = (char*)d_out;

    prep<<<dim3(288), dim3(256), 0, stream>>>(w_in, b_in, w_out, wst, wos, brr);
    prep_x<<<dim3(24576), dim3(256), 0, stream>>>(x, xbf);
    qkv_attn<<<dim3(12288), dim3(512), 0, stream>>>(xbf, wst, brr, att);
    out_proj<<<dim3(3072), dim3(256), 0, stream>>>(att, wos, b_out, out);
}